// Round 5
// baseline (354.575 us; speedup 1.0000x reference)
//
#include <hip/hip_runtime.h>

typedef short bf16x8 __attribute__((ext_vector_type(8)));
typedef float f32x4 __attribute__((ext_vector_type(4)));

#define K_CLUSTERS 512
#define DIM 64
#define ROWS_PER_BLOCK 64   // per row-group: 4 subtiles of 16 rows
#define NSUB 4
#define QPAD 520            // 512 + 8 dwords: breaks pow2 bank stride
#define GRID 512            // persistent: 2 blocks/CU on 256 CUs

__device__ __forceinline__ unsigned short f32_to_bf16_rne(float f) {
    unsigned int u = __float_as_uint(f);
    u += 0x7fffu + ((u >> 16) & 1u);
    return (unsigned short)(u >> 16);
}
__device__ __forceinline__ float bf16_bits_to_f32(unsigned short h) {
    return __uint_as_float(((unsigned int)h) << 16);
}

// Zero the loss accumulator (graph-capture-safe; proven pattern from r0-r3).
__global__ void zero_loss(float* __restrict__ loss_out) {
    loss_out[0] = 0.0f;
}

// LDS-only barrier: lgkmcnt wait + s_barrier, NO vmcnt drain (q-stores are
// never waited on inside a group's subtile loop; they drain under compute).
#define BARRIER() do {                                      \
    asm volatile("s_waitcnt lgkmcnt(0)" ::: "memory");      \
    __builtin_amdgcn_s_barrier();                           \
} while (0)

// Fused persistent kernel (round-4 structure, re-submitted with the
// hipMemsetAsync replaced by a zero_loss kernel after the container failure):
//  * prep_centers folded in: each block builds its own bf16 hi/lo B-fragments
//    and ||c||^2 from raw c (128 KB, L2/L3-resident) -- no workspace.
//  * persistent grid: 512 blocks (2/CU), grid-stride over row-groups (4 each).
//    B-fragment build amortized 4x, block start/end overhead 4x fewer,
//    loss atomics 2048 -> 512; group g+1's z-prologue overlaps g's stores.
// Math unchanged: softmax(-(zsq+csq-2zc)) == softmax(2zc-csq);
// loss = mean(zsq) + mean(sum_j q_j*(csq_j-2cross_j)).
__global__ __launch_bounds__(512, 4)
void cluster_kernel(const float* __restrict__ z,
                    const float* __restrict__ c,
                    float* __restrict__ q_out,
                    float* __restrict__ loss_out,
                    float inv_b, int totgroups) {
    __shared__ __align__(16) short a_hi_s[NSUB][16][72];   // 144B rows = 9x16B
    __shared__ __align__(16) short a_lo_s[NSUB][16][72];
    __shared__ __align__(16) float q_s[16][QPAD];          // 33.3 KB q transpose
    __shared__ __align__(16) float2 red_s[2][8][16];       // [parity][wave][row]
    __shared__ float wloss_s[8];

    const int tid  = threadIdx.x;
    const int lane = tid & 63;
    const int wave = tid >> 6;
    const int m    = lane & 15;   // A row / B,C col within tile
    const int qd   = lane >> 4;   // quad
    const int srow = tid >> 5;
    const int scol = (tid & 31) * 2;

    // ---- B fragments from raw c: hi/lo bf16 split + csq, in-register ----
    // Lane (m,qd), tile t: col = wave*64+t*16+m, dims kg*32+qd*8 .. +8.
    // The 4 lanes sharing m cover all 64 dims exactly once -> csq via
    // shfl_xor 16,32 (qd-axis reduction).
    bf16x8 bh[4][2], bl[4][2];
    float csq[4];
    #pragma unroll
    for (int t = 0; t < 4; ++t) {
        const int col = wave * 64 + t * 16 + m;
        float part = 0.0f;
        #pragma unroll
        for (int kg = 0; kg < 2; ++kg) {
            const float* cp = c + (long)col * DIM + kg * 32 + qd * 8;
            bf16x8 h8, l8;
            #pragma unroll
            for (int j = 0; j < 8; ++j) {
                const float v = cp[j];
                part = __builtin_fmaf(v, v, part);
                const unsigned short h = f32_to_bf16_rne(v);
                h8[j] = (short)h;
                l8[j] = (short)f32_to_bf16_rne(v - bf16_bits_to_f32(h));
            }
            bh[t][kg] = h8;
            bl[t][kg] = l8;
        }
        part += __shfl_xor(part, 16, 64);
        part += __shfl_xor(part, 32, 64);
        csq[t] = part;
    }

    float lsum = 0.0f;   // per-lane sum of q*(csq-2cross)
    float zpart = 0.0f;  // per-thread sum of z^2 (separable loss term)

    for (int grp = blockIdx.x; grp < totgroups; grp += GRID) {
        const long rb = (long)grp * ROWS_PER_BLOCK;
        const float2* zin = (const float2*)(z + rb * DIM);   // 2048 float2

        // ---- prologue: load group's z rows, cvt+stage to LDS ----
        // (safe to overwrite a_*: prior group's frag reads are >=2 barriers
        //  old; prior q_s reads are drained by this wave's own lgkmcnt(0)
        //  at the BARRIER below, and ordered block-wide by the barrier.)
        #pragma unroll
        for (int k = 0; k < NSUB; ++k) {
            float2 v = zin[k * 512 + tid];
            zpart += v.x * v.x + v.y * v.y;
            unsigned short hx = f32_to_bf16_rne(v.x);
            unsigned short lx = f32_to_bf16_rne(v.x - bf16_bits_to_f32(hx));
            unsigned short hy = f32_to_bf16_rne(v.y);
            unsigned short ly = f32_to_bf16_rne(v.y - bf16_bits_to_f32(hy));
            *(unsigned int*)&a_hi_s[k][srow][scol] = (unsigned int)hx | ((unsigned int)hy << 16);
            *(unsigned int*)&a_lo_s[k][srow][scol] = (unsigned int)lx | ((unsigned int)ly << 16);
        }
        BARRIER();   // A staged; read-only for the rest of this group

        for (int s = 0; s < NSUB; ++s) {
            // ---- A fragments: lane m holds row m, k = kg*32 + qd*8 .. ----
            bf16x8 ah[2], al[2];
            #pragma unroll
            for (int kg = 0; kg < 2; ++kg) {
                ah[kg] = *(const bf16x8*)&a_hi_s[s][m][kg * 32 + qd * 8];
                al[kg] = *(const bf16x8*)&a_lo_s[s][m][kg * 32 + qd * 8];
            }

            // ---- cross = z_hi.c_hi + z_hi.c_lo + z_lo.c_hi ----
            f32x4 acc[4];
            #pragma unroll
            for (int t = 0; t < 4; ++t) acc[t] = (f32x4){0.f, 0.f, 0.f, 0.f};
            #pragma unroll
            for (int kg = 0; kg < 2; ++kg) {
                #pragma unroll
                for (int t = 0; t < 4; ++t) {
                    acc[t] = __builtin_amdgcn_mfma_f32_16x16x32_bf16(ah[kg], bh[t][kg], acc[t], 0, 0, 0);
                    acc[t] = __builtin_amdgcn_mfma_f32_16x16x32_bf16(ah[kg], bl[t][kg], acc[t], 0, 0, 0);
                    acc[t] = __builtin_amdgcn_mfma_f32_16x16x32_bf16(al[kg], bh[t][kg], acc[t], 0, 0, 0);
                }
            }

            // ---- dd = csq - 2*cross (zsq cancels in softmax) ----
            float dd[4][4];
            #pragma unroll
            for (int t = 0; t < 4; ++t)
                #pragma unroll
                for (int r = 0; r < 4; ++r)
                    dd[t][r] = __builtin_fmaf(-2.0f, acc[t][r], csq[t]);

            // ---- per-wave partials: min + sum-exp (16-lane qd-group) ----
            float mnw[4], sw4[4];
            #pragma unroll
            for (int r = 0; r < 4; ++r) {
                float mn0 = fminf(fminf(dd[0][r], dd[1][r]), fminf(dd[2][r], dd[3][r]));
                #pragma unroll
                for (int off = 1; off < 16; off <<= 1)
                    mn0 = fminf(mn0, __shfl_xor(mn0, off, 64));
                mnw[r] = mn0;
            }
            #pragma unroll
            for (int r = 0; r < 4; ++r) {
                float s0 = (__expf(mnw[r] - dd[0][r]) + __expf(mnw[r] - dd[1][r]))
                         + (__expf(mnw[r] - dd[2][r]) + __expf(mnw[r] - dd[3][r]));
                #pragma unroll
                for (int off = 1; off < 16; off <<= 1)
                    s0 += __shfl_xor(s0, off, 64);
                sw4[r] = s0;
            }
            if (m == 0) {
                #pragma unroll
                for (int r = 0; r < 4; ++r)
                    red_s[s & 1][wave][qd * 4 + r] = make_float2(mnw[r], sw4[r]);
            }
            BARRIER();   // sync A: partials visible

            // ---- combine across waves (row = m; broadcast reads) ----
            float mn = red_s[s & 1][0][m].x;
            #pragma unroll
            for (int w2 = 1; w2 < 8; ++w2) mn = fminf(mn, red_s[s & 1][w2][m].x);
            float S = 0.0f;
            #pragma unroll
            for (int w2 = 0; w2 < 8; ++w2) {
                float2 p = red_s[s & 1][w2][m];
                S = __builtin_fmaf(p.y, __expf(mn - p.x), S);
            }
            const float invS = 1.0f / S;

            float mnr[4], fsr[4];
            #pragma unroll
            for (int r = 0; r < 4; ++r) {
                mnr[r] = __shfl(mn,   qd * 4 + r, 64);
                fsr[r] = __shfl(invS, qd * 4 + r, 64);
            }

            // ---- q = exp(mn - dd)*invS -> LDS transpose ----
            #pragma unroll
            for (int r = 0; r < 4; ++r) {
                const int row = qd * 4 + r;
                #pragma unroll
                for (int t = 0; t < 4; ++t) {
                    const float qv = __expf(mnr[r] - dd[t][r]) * fsr[r];
                    q_s[row][wave * 64 + t * 16 + m] = qv;
                    lsum = __builtin_fmaf(qv, dd[t][r], lsum);
                }
            }
            BARRIER();   // sync B: q_s complete

            // ---- coalesced q write: PLAIN dwordx4, 1 KB/instr/wave ----
            const long rbase = rb + (long)s * 16;
            #pragma unroll
            for (int rr = 0; rr < 2; ++rr) {
                const int row = wave * 2 + rr;
                const f32x4* src = (const f32x4*)&q_s[row][0];
                f32x4 v0 = src[lane];
                f32x4 v1 = src[64 + lane];
                f32x4* dst = (f32x4*)(q_out + (rbase + row) * K_CLUSTERS);
                dst[lane]      = v0;
                dst[64 + lane] = v1;
            }
            // no trailing barrier: next q_s writes are 2 barriers away
        }
    }

    // ---- final loss: zsq separable term + q*dd partials ----
    float tot = lsum + zpart;
    #pragma unroll
    for (int off = 1; off < 64; off <<= 1) tot += __shfl_xor(tot, off, 64);
    if (lane == 0) wloss_s[wave] = tot;
    __syncthreads();
    if (tid == 0) {
        float t0 = 0.f;
        #pragma unroll
        for (int w = 0; w < 8; ++w) t0 += wloss_s[w];
        atomicAdd(loss_out, t0 * inv_b);
    }
}

extern "C" void kernel_launch(void* const* d_in, const int* in_sizes, int n_in,
                              void* d_out, int out_size, void* d_ws, size_t ws_size,
                              hipStream_t stream) {
    const float* z = (const float*)d_in[0];
    const float* c = (const float*)d_in[1];
    const int B = in_sizes[0] / DIM;              // 131072
    float* q_out = (float*)d_out;
    float* loss_out = q_out + (size_t)B * K_CLUSTERS;

    zero_loss<<<1, 1, 0, stream>>>(loss_out);

    const int totgroups = B / ROWS_PER_BLOCK;     // 2048
    const int grid = totgroups < GRID ? totgroups : GRID;
    cluster_kernel<<<grid, 512, 0, stream>>>(z, c, q_out, loss_out,
                                             1.0f / (float)B, totgroups);
}